// Round 3
// baseline (137.124 us; speedup 1.0000x reference)
//
#include <hip/hip_runtime.h>

// EmbeddingWithDropout: out[b,s,:] = weight[x[b,s],:] * ((u[x[b,s]] >= 0.1) ? 1/0.9 : 0)
// x: [64,2048] int32, weight: [100000,128] fp32, u: [100000] fp32
// out: [64,2048,128] fp32
//
// MEASUREMENT PROBE ROUND: the embed kernel never appears in the rocprof top-5
// (all fills @43us), so its device time is <42us while dur_us=114us -- the
// timed graph is dominated by harness poison fills. To measure the kernel's
// true device time, launch it TWICE (idempotent: same inputs -> same output).
// delta(dur_us) vs round 0/2 == one kernel instance's device time.
//
// Kernel itself: reverted to the leanest structure (1 float4/thread, coalesced,
// nt store) -- the 8x ILP variant was neutral, so simplest wins.

#define DIM 128
#define VEC_PER_ROW (DIM / 4)   // 32 float4 per row
#define BLOCK 256

typedef float f4 __attribute__((ext_vector_type(4)));

__global__ __launch_bounds__(BLOCK) void embed_dropout_kernel(
    const int* __restrict__ x,
    const float* __restrict__ weight,
    const float* __restrict__ u,
    f4* __restrict__ out,
    int n_tokens)
{
    int gid = blockIdx.x * BLOCK + threadIdx.x;    // one float4 per thread
    int token = gid >> 5;                          // /32
    int off   = gid & 31;
    if (token >= n_tokens) return;

    int idx = x[token];
    float keep = (u[idx] >= 0.1f) ? (1.0f / 0.9f) : 0.0f;

    const f4* wrow = reinterpret_cast<const f4*>(weight)
                     + (size_t)idx * VEC_PER_ROW + off;
    f4 v = *wrow * keep;
    __builtin_nontemporal_store(v, &out[gid]);
}

extern "C" void kernel_launch(void* const* d_in, const int* in_sizes, int n_in,
                              void* d_out, int out_size, void* d_ws, size_t ws_size,
                              hipStream_t stream) {
    const int*   x      = (const int*)d_in[0];     // [64*2048]
    const float* weight = (const float*)d_in[1];   // [100000*128]
    const float* u      = (const float*)d_in[2];   // [100000]
    f4*          out    = (f4*)d_out;

    int n_tokens = in_sizes[0];                    // 131072
    int n_vec4   = n_tokens * VEC_PER_ROW;         // 4194304 float4 elements
    int grid  = (n_vec4 + BLOCK - 1) / BLOCK;      // 16384 blocks

    // PROBE: two identical launches. Second is idempotent; the dur_us delta
    // vs the single-launch baseline measures one kernel instance exactly.
    embed_dropout_kernel<<<grid, BLOCK, 0, stream>>>(x, weight, u, out, n_tokens);
    embed_dropout_kernel<<<grid, BLOCK, 0, stream>>>(x, weight, u, out, n_tokens);
}

// Round 4
// 116.786 us; speedup vs baseline: 1.1741x; 1.1741x over previous
//
#include <hip/hip_runtime.h>

// EmbeddingWithDropout: out[b,s,:] = weight[x[b,s],:] * ((u[x[b,s]] >= 0.1) ? 1/0.9 : 0)
// x: [64,2048] int32, weight: [100000,128] fp32, u: [100000] fp32
// out: [64,2048,128] fp32
//
// FINAL (probe reverted). Measured facts (R0-R3):
//  - dur_us=114 is dominated by 2 harness poison fills (2x43us @6.3TB/s);
//    the embed kernel itself is ~22us (measured via idempotent double-launch
//    probe: 137.1 - 114.4 = 22.7us).
//  - Kernel compulsory traffic ~135 MB -> roofline 21.5us @ 6.3TB/s.
//    The kernel runs AT the streaming roofline despite being a random gather
//    (512B rows fully consumed, 32 lanes x 16B coalesced).
//  - ILP-8 phase-split (R2) was neutral -> not latency-bound; keep simplest.
//  - nt store keeps the 67MB output stream from evicting weight rows; neutral
//    in time, kept for L3 hygiene.

#define DIM 128
#define VEC_PER_ROW (DIM / 4)   // 32 float4 per row
#define BLOCK 256

typedef float f4 __attribute__((ext_vector_type(4)));

__global__ __launch_bounds__(BLOCK) void embed_dropout_kernel(
    const int* __restrict__ x,
    const float* __restrict__ weight,
    const float* __restrict__ u,
    f4* __restrict__ out,
    int n_tokens)
{
    int gid = blockIdx.x * BLOCK + threadIdx.x;    // one float4 per thread
    int token = gid >> 5;                          // /32
    int off   = gid & 31;
    if (token >= n_tokens) return;

    int idx = x[token];
    float keep = (u[idx] >= 0.1f) ? (1.0f / 0.9f) : 0.0f;

    const f4* wrow = reinterpret_cast<const f4*>(weight)
                     + (size_t)idx * VEC_PER_ROW + off;
    f4 v = *wrow * keep;
    __builtin_nontemporal_store(v, &out[gid]);
}

extern "C" void kernel_launch(void* const* d_in, const int* in_sizes, int n_in,
                              void* d_out, int out_size, void* d_ws, size_t ws_size,
                              hipStream_t stream) {
    const int*   x      = (const int*)d_in[0];     // [64*2048]
    const float* weight = (const float*)d_in[1];   // [100000*128]
    const float* u      = (const float*)d_in[2];   // [100000]
    f4*          out    = (f4*)d_out;

    int n_tokens = in_sizes[0];                    // 131072
    int n_vec4   = n_tokens * VEC_PER_ROW;         // 4194304 float4 elements
    int grid  = (n_vec4 + BLOCK - 1) / BLOCK;      // 16384 blocks

    embed_dropout_kernel<<<grid, BLOCK, 0, stream>>>(x, weight, u, out, n_tokens);
}